// Round 14
// baseline (484.886 us; speedup 1.0000x reference)
//
#include <hip/hip_runtime.h>
#include <hip/hip_bf16.h>
#include <math.h>

#define B_ROWS 32768

typedef __attribute__((ext_vector_type(8)))  short        s8v;
typedef __attribute__((ext_vector_type(4)))  float        f4v;
typedef __attribute__((ext_vector_type(2)))  unsigned int u2v;
typedef __attribute__((ext_vector_type(4)))  unsigned int u4v;

__device__ __forceinline__ short f2bf(float f){            // f32 -> bf16 RNE
  unsigned u = __builtin_bit_cast(unsigned, f);
  u = (u + 0x7fffu + ((u >> 16) & 1u)) >> 16;
  return (short)u;
}
// packed pair convert (RNE) — builtin path (inline-asm variant NaN'd in r2/r7)
__device__ __forceinline__ unsigned cpk(float a, float b){
  __hip_bfloat16_raw lo = (__hip_bfloat16_raw)__float2bfloat16(a);
  __hip_bfloat16_raw hi = (__hip_bfloat16_raw)__float2bfloat16(b);
  return (unsigned)lo.x | ((unsigned)hi.x << 16);
}
__device__ __forceinline__ float bf_lo(unsigned u){ return __builtin_bit_cast(float, u << 16); }
__device__ __forceinline__ float bf_hi(unsigned u){ return __builtin_bit_cast(float, u & 0xffff0000u); }

// fast atan: range-reduce via v_rcp + deg-9 odd minimax (|err| ~1e-4 << 0.1 tol)
__device__ __forceinline__ float atan_f(float t){
  float a = fabsf(t);
  bool big = a > 1.0f;
  float u = big ? __builtin_amdgcn_rcpf(t) : t;
  float s = u * u;
  float p = fmaf(fmaf(fmaf(fmaf(s, 0.0208351f, -0.0851330f), s, 0.1801410f), s, -0.3302995f), s, 0.9998660f);
  p = u * p;
  float base = __builtin_copysignf(1.57079633f, t);
  return big ? base - p : p;
}

#define MFMA16(A,B,C) __builtin_amdgcn_mfma_f32_16x16x32_bf16((A),(B),(C),0,0,0)

typedef __attribute__((address_space(1))) const unsigned int gu32;
typedef __attribute__((address_space(3))) unsigned int lu32;
__device__ __forceinline__ void gl_lds16(const unsigned short* g, char* l){
  __builtin_amdgcn_global_load_lds((gu32*)(const void*)g, (lu32*)(void*)l, 16, 0, 0);
}

// ---------------- LDS layout (bytes) — 161280 <= 160KiB, 1 WG x 16 waves/CU ----------------
#define OXFT 0          // f32 [64 dims][132] x-state transposed
#define XFT_S 132
#define OXHB 33792      // bf16 [128 batch][40] current x-half, batch-major (xk source)
#define XHB_S 40
#define OHB  44032      // bf16 [128 batch][136] hidden chunk; slots 0,1 alias (17408B each)
#define HB_S 136
#define OW1  78848      // 2 x 40960B W1 chunk double buffer, frag-linear (40 tiles x 1KB)
#define W1BUF 40960
#define OLJ  160768     // f32[128]
#define SM_SZ 161280
// reduce slots: bf16 [128][68] (17408B). Slots 0,1 alias HB; slots 2,3 alias W1 buf1.
// Liveness: written after chunk-3 barrier (HB + buf1 dead; next-MLP chunk0 DMA -> buf0);
// consumed in coupling; buf1's next DMA (chunk1) issues only after the coupling barrier.
#define SL_S 68
#define SLOT_B 17408

// ws (bf16, fragment-linear): W1 [24][4 chunks][40 tiles][512], W2 [24][4 c][4 hw][4 ot][512]
#define WF_W2 1966080
#define W_TOTAL 2752512

// -------- one-time f32 -> bf16 fragment-linear rearrangement (identical to r10) --------
__global__ void cvtw_frag(const float* __restrict__ s1w1, const float* __restrict__ s1w2,
                          const float* __restrict__ s2w1, const float* __restrict__ s2w2,
                          unsigned short* __restrict__ dst)
{
  long t = (long)blockIdx.x * blockDim.x + threadIdx.x;
  if (t >= W_TOTAL) return;
  float v;
  if (t < WF_W2){
    int m = (int)(t / 81920); int r = (int)(t - (long)m*81920);
    int c = r / 20480;  int r2 = r - c*20480;
    int tile = r2 >> 9; int r3 = r2 & 511;
    int lane = r3 >> 3; int e = r3 & 7;
    int rg = tile / 5,  kk = tile - rg*5;
    int l15 = lane & 15, lq = lane >> 4;
    int h  = c*128 + rg*16 + l15;
    int ki = kk*32 + lq*8 + e;
    const float* src = (m & 1) ? s1w1 : s2w1;
    v = src[(size_t)(m >> 1)*81920 + h*160 + ki];
  } else {
    long u = t - WF_W2;
    int m = (int)(u / 32768); int r = (int)(u - (long)m*32768);
    int g = r >> 9; int r3 = r & 511;
    int lane = r3 >> 3; int e = r3 & 7;
    int c = g >> 4, hw = (g >> 2) & 3, ot = g & 3;
    int l15 = lane & 15, lq = lane >> 4;
    int o = ot*16 + l15;
    int h = c*128 + hw*32 + lq*8 + e;
    const float* src = (m & 1) ? s1w2 : s2w2;
    v = src[(size_t)(m >> 1)*32768 + o*512 + h];
  }
  dst[t] = (unsigned short)f2bf(v);
}

// DMA one 128-hidden W1 chunk (40 x 1KB tiles) spread over 16 waves
__device__ __forceinline__ void dma_w1(const unsigned short* gsec, char* lb, int wave, int lane){
  gl_lds16(gsec + (size_t)wave*512 + lane*8,        lb + wave*1024);
  gl_lds16(gsec + (size_t)(wave+16)*512 + lane*8,   lb + (wave+16)*1024);
  if (wave < 8)
    gl_lds16(gsec + (size_t)(wave+32)*512 + lane*8, lb + (wave+32)*1024);
}

__global__ __launch_bounds__(1024) void cinn_w16(
    const float* __restrict__ q, const float* __restrict__ Hg,
    const int* __restrict__ perms,
    const float* __restrict__ ls_g, const float* __restrict__ bi_g,
    const float* __restrict__ s1b1, const float* __restrict__ s1b2,
    const float* __restrict__ s2b1, const float* __restrict__ s2b2,
    const unsigned short* __restrict__ wbf,
    float* __restrict__ outz, float* __restrict__ outlj)
{
  __shared__ __align__(16) char sm[SM_SZ];
  const int tid = threadIdx.x;
  const int rowbase = blockIdx.x * 128;
  const int lane = tid & 63, wave = tid >> 6;     // 16 waves
  const int ng = wave >> 2, hw = wave & 3;        // ng: 32-batch group; hw: k-split group
  const int l15 = lane & 15, lq = lane >> 4;

  float* XFT = (float*)(sm + OXFT);
  short* XHB = (short*)(sm + OXHB);
  short* HB  = (short*)(sm + OHB);
  float* LOGJ= (float*)(sm + OLJ);

  // init XFT from q (coalesced read, strided LDS write, once)
  {
    int b = tid >> 3, j = tid & 7;
    const float* src = q + (size_t)(rowbase + b)*64 + j*8;
    f4v v0 = *(const f4v*)src;
    f4v v1 = *(const f4v*)(src + 4);
    #pragma unroll
    for (int jj = 0; jj < 4; ++jj){
      XFT[(j*8 + jj)*XFT_S + b]     = v0[jj];
      XFT[(j*8 + 4 + jj)*XFT_S + b] = v1[jj];
    }
  }
  if (tid < 128) LOGJ[tid] = 0.f;
  __syncthreads();

  // H-part B-fragments: loaded ONCE, register-resident (2 nt x 4 kk)
  s8v hfr[2][4];
  #pragma unroll
  for (int nt = 0; nt < 2; ++nt){
    int b = rowbase + ng*32 + nt*16 + l15;
    #pragma unroll
    for (int kkh = 0; kkh < 4; ++kkh){
      const float* hp = Hg + (size_t)b*128 + kkh*32 + lq*8;
      f4v a = *(const f4v*)hp;
      f4v c = *(const f4v*)(hp + 4);
      u4v u = {cpk(a[0],a[1]), cpk(a[2],a[3]), cpk(c[0],c[1]), cpk(c[2],c[3])};
      hfr[nt][kkh] = __builtin_bit_cast(s8v, u);
    }
  }

  // prologue: DMA MLP0 chunk0 -> buf0 (drained by the m=0 permute barriers)
  dma_w1(wbf, sm + OW1, wave, lane);

  for (int m = 0; m < 24; ++m){
    const int bp = m & 1;
    const unsigned short* w1sec = wbf + (size_t)m*81920;
    const unsigned short* w2sec = wbf + WF_W2 + (size_t)m*32768;
    const float* b1p = (bp ? s1b1 : s2b1) + (m >> 1)*512;
    const float* b2p = (bp ? s1b2 : s2b2) + (m >> 1)*64;

    if (!bp){
      int blk = m >> 1;
      int   pd = perms[blk*64 + lane];
      float e  = __expf(ls_g[blk*64 + lane]);
      float bi = bi_g[blk*64 + lane];
      int bg = wave;                       // 16 groups x 8 batch
      f4v v[2];
      #pragma unroll
      for (int i = 0; i < 2; ++i)
        v[i] = *(const f4v*)(XFT + pd*XFT_S + bg*8 + 4*i);
      __syncthreads();
      #pragma unroll
      for (int i = 0; i < 2; ++i){
        #pragma unroll
        for (int jj = 0; jj < 4; ++jj) v[i][jj] = fmaf(v[i][jj], e, bi);
        *(f4v*)(XFT + lane*XFT_S + bg*8 + 4*i) = v[i];
      }
      if (lane >= 32){   // x2 -> XHB (even MLP's x-input)
        #pragma unroll
        for (int i = 0; i < 2; ++i)
          #pragma unroll
          for (int jj = 0; jj < 4; ++jj)
            XHB[(bg*8 + 4*i + jj)*XHB_S + (lane - 32)] = f2bf(v[i][jj]);
      }
      __syncthreads();
    }

    // xk: one b128 per nt from XHB (batch-major bf16)
    s8v xk[2];
    #pragma unroll
    for (int nt = 0; nt < 2; ++nt)
      xk[nt] = *(const s8v*)(XHB + (ng*32 + nt*16 + l15)*XHB_S + lq*8);

    f4v b2v[4];
    if (hw == 0){
      #pragma unroll
      for (int ot = 0; ot < 4; ++ot)
        b2v[ot] = *(const f4v*)(b2p + ot*16 + lq*4);
    }

    f4v racc[4][2];
    #pragma unroll
    for (int ot = 0; ot < 4; ++ot)
      #pragma unroll
      for (int nt = 0; nt < 2; ++nt)
        racc[ot][nt] = (f4v){0.f,0.f,0.f,0.f};

    #pragma unroll
    for (int c = 0; c < 4; ++c){
      // DMA next chunk into the other buffer (full chunk of compute covers it)
      if (!(m == 23 && c == 3)){
        const unsigned short* gsec = (c < 3) ? (w1sec + (c+1)*20480) : (w1sec + 81920);
        dma_w1(gsec, sm + OW1 + ((c+1)&1)*W1BUF, wave, lane);
      }
      // W2 A-frags (frag-linear, coalesced 1KB/wave), b1
      s8v w2c[4];
      #pragma unroll
      for (int ot = 0; ot < 4; ++ot)
        w2c[ot] = *(const s8v*)(w2sec + (size_t)((c*4 + hw)*4 + ot)*512 + lane*8);
      f4v b1v0 = *(const f4v*)(b1p + c*128 + hw*32 + lq*4);
      f4v b1v1 = *(const f4v*)(b1p + c*128 + hw*32 + 16 + lq*4);

      // ---- GEMM1 chunk c: hidden rows hw*32 + {0,16} (frag-linear LDS reads)
      const short* W1c = (const short*)(sm + OW1 + (c&1)*W1BUF);
      f4v acc[2][2];
      #pragma unroll
      for (int mt = 0; mt < 2; ++mt)
        #pragma unroll
        for (int nt = 0; nt < 2; ++nt) acc[mt][nt] = (f4v){0.f,0.f,0.f,0.f};
      #pragma unroll
      for (int kk = 0; kk < 5; ++kk){
        s8v a0 = *(const s8v*)(W1c + ((hw*2 + 0)*5 + kk)*512 + lane*8);
        s8v a1 = *(const s8v*)(W1c + ((hw*2 + 1)*5 + kk)*512 + lane*8);
        #pragma unroll
        for (int nt = 0; nt < 2; ++nt){
          s8v bb = (kk == 0) ? xk[nt] : hfr[nt][kk-1];
          acc[0][nt] = MFMA16(a0, bb, acc[0][nt]);
          acc[1][nt] = MFMA16(a1, bb, acc[1][nt]);
        }
      }
      // bias + relu + pack -> own HB region (in-wave, disjoint per (ng,hw))
      #pragma unroll
      for (int mt = 0; mt < 2; ++mt){
        f4v bv = mt ? b1v1 : b1v0;
        #pragma unroll
        for (int nt = 0; nt < 2; ++nt){
          float h0 = fmaxf(acc[mt][nt][0] + bv[0], 0.f);
          float h1 = fmaxf(acc[mt][nt][1] + bv[1], 0.f);
          float h2 = fmaxf(acc[mt][nt][2] + bv[2], 0.f);
          float h3 = fmaxf(acc[mt][nt][3] + bv[3], 0.f);
          *(u2v*)(HB + (ng*32 + nt*16 + l15)*HB_S + hw*32 + mt*16 + lq*4) = (u2v){cpk(h0,h1), cpk(h2,h3)};
        }
      }
      // ---- GEMM2 k-slice: read back OWN 32 rows (in-wave, no barrier)
      #pragma unroll
      for (int nt = 0; nt < 2; ++nt){
        s8v bb = *(const s8v*)(HB + (ng*32 + nt*16 + l15)*HB_S + hw*32 + lq*8);
        #pragma unroll
        for (int ot = 0; ot < 4; ++ot)
          racc[ot][nt] = MFMA16(w2c[ot], bb, racc[ot][nt]);
      }
      __syncthreads();   // buf(c&1) free; buf((c+1)&1) DMA drained
    }

    // ---- 4 reduce slots (0,1 alias dead HB; 2,3 alias dead W1 buf1), +b2 on hw0
    {
      short* SL = (hw < 2) ? (short*)(sm + OHB + hw*SLOT_B)
                           : (short*)(sm + OW1 + W1BUF + (hw-2)*SLOT_B);
      #pragma unroll
      for (int ot = 0; ot < 4; ++ot)
        #pragma unroll
        for (int nt = 0; nt < 2; ++nt){
          float r0 = racc[ot][nt][0], r1 = racc[ot][nt][1];
          float r2 = racc[ot][nt][2], r3 = racc[ot][nt][3];
          if (hw == 0){ r0 += b2v[ot][0]; r1 += b2v[ot][1]; r2 += b2v[ot][2]; r3 += b2v[ot][3]; }
          *(u2v*)(SL + (ng*32 + nt*16 + l15)*SL_S + ot*16 + lq*4) = (u2v){cpk(r0,r1), cpk(r2,r3)};
        }
    }
    __syncthreads();

    // ---- coupling: sum 4 slots, le = 0.636*atan(rL); y = exp(le)*x_half + rR
    {
      int b = tid & 127, dg = tid >> 7;            // 8 dim-groups x 4 dims
      float le[4] = {0,0,0,0}, ra[4] = {0,0,0,0};
      #pragma unroll
      for (int ms = 0; ms < 4; ++ms){
        const short* SL = (ms < 2) ? (const short*)(sm + OHB + ms*SLOT_B)
                                   : (const short*)(sm + OW1 + W1BUF + (ms-2)*SLOT_B);
        u2v L = *(const u2v*)(SL + b*SL_S + dg*4);
        u2v R = *(const u2v*)(SL + b*SL_S + 32 + dg*4);
        le[0]+=bf_lo(L[0]); le[1]+=bf_hi(L[0]); le[2]+=bf_lo(L[1]); le[3]+=bf_hi(L[1]);
        ra[0]+=bf_lo(R[0]); ra[1]+=bf_hi(R[0]); ra[2]+=bf_lo(R[1]); ra[3]+=bf_hi(R[1]);
      }
      float part = 0.f, y[4];
      #pragma unroll
      for (int j = 0; j < 4; ++j){
        float l = 0.636f * atan_f(le[j]);
        int d = bp*32 + dg*4 + j;
        y[j] = __expf(l) * XFT[d*XFT_S + b] + ra[j];
        XFT[d*XFT_S + b] = y[j];
        part += l;
      }
      if (!bp)   // y1 feeds the odd MLP's xk
        *(u2v*)(XHB + b*XHB_S + dg*4) = (u2v){cpk(y[0],y[1]), cpk(y[2],y[3])};
      atomicAdd(&LOGJ[b], part);
    }
    __syncthreads();
  }

  // output: transpose back, coalesced global writes
  {
    int b = tid >> 3, j = tid & 7;
    float* dst = outz + (size_t)(rowbase + b)*64 + j*8;
    f4v w0, w1;
    #pragma unroll
    for (int jj = 0; jj < 4; ++jj){
      w0[jj] = XFT[(j*8 + jj)*XFT_S + b];
      w1[jj] = XFT[(j*8 + 4 + jj)*XFT_S + b];
    }
    *(f4v*)dst = w0;
    *(f4v*)(dst + 4) = w1;
  }
  if (tid < 128){
    float p = 0.f;
    #pragma unroll
    for (int k = 0; k < 12; ++k) p += ls_g[k*64 + lane];
    #pragma unroll
    for (int off = 1; off < 64; off <<= 1) p += __shfl_xor(p, off);
    outlj[rowbase + tid] = LOGJ[tid] + p;
  }
}

extern "C" void kernel_launch(void* const* d_in, const int* in_sizes, int n_in,
                              void* d_out, int out_size, void* d_ws, size_t ws_size,
                              hipStream_t stream)
{
  const float* q    = (const float*)d_in[0];
  const float* Hg   = (const float*)d_in[1];
  const int*   perms= (const int*)  d_in[2];
  const float* ls   = (const float*)d_in[3];
  const float* bi   = (const float*)d_in[4];
  const float* s1W1 = (const float*)d_in[5];
  const float* s1b1 = (const float*)d_in[6];
  const float* s1W2 = (const float*)d_in[7];
  const float* s1b2 = (const float*)d_in[8];
  const float* s2W1 = (const float*)d_in[9];
  const float* s2b1 = (const float*)d_in[10];
  const float* s2W2 = (const float*)d_in[11];
  const float* s2b2 = (const float*)d_in[12];
  float* outz  = (float*)d_out;
  float* outlj = outz + (size_t)B_ROWS * 64;

  unsigned short* wbf = (unsigned short*)d_ws;
  cvtw_frag<<<2688, 1024, 0, stream>>>(s1W1, s1W2, s2W1, s2W2, wbf);
  cinn_w16<<<256, 1024, 0, stream>>>(q, Hg, perms, ls, bi,
                                     s1b1, s1b2, s2b1, s2b2,
                                     wbf, outz, outlj);
}

// Round 16
// 264.495 us; speedup vs baseline: 1.8332x; 1.8332x over previous
//
#include <hip/hip_runtime.h>
#include <hip/hip_bf16.h>
#include <math.h>

#define B_ROWS 32768

typedef __attribute__((ext_vector_type(8)))  short        s8v;
typedef __attribute__((ext_vector_type(4)))  float        f4v;
typedef __attribute__((ext_vector_type(2)))  unsigned int u2v;
typedef __attribute__((ext_vector_type(4)))  unsigned int u4v;

__device__ __forceinline__ short f2bf(float f){            // f32 -> bf16 RNE
  unsigned u = __builtin_bit_cast(unsigned, f);
  u = (u + 0x7fffu + ((u >> 16) & 1u)) >> 16;
  return (short)u;
}
// packed pair convert (RNE) — builtin path (inline-asm variant NaN'd in r2/r7)
__device__ __forceinline__ unsigned cpk(float a, float b){
  __hip_bfloat16_raw lo = (__hip_bfloat16_raw)__float2bfloat16(a);
  __hip_bfloat16_raw hi = (__hip_bfloat16_raw)__float2bfloat16(b);
  return (unsigned)lo.x | ((unsigned)hi.x << 16);
}
__device__ __forceinline__ float bf_lo(unsigned u){ return __builtin_bit_cast(float, u << 16); }
__device__ __forceinline__ float bf_hi(unsigned u){ return __builtin_bit_cast(float, u & 0xffff0000u); }

// fast atan: range-reduce via v_rcp + deg-9 odd minimax (|err| ~1e-4 << 0.1 tol)
__device__ __forceinline__ float atan_f(float t){
  float a = fabsf(t);
  bool big = a > 1.0f;
  float u = big ? __builtin_amdgcn_rcpf(t) : t;
  float s = u * u;
  float p = fmaf(fmaf(fmaf(fmaf(s, 0.0208351f, -0.0851330f), s, 0.1801410f), s, -0.3302995f), s, 0.9998660f);
  p = u * p;
  float base = __builtin_copysignf(1.57079633f, t);
  return big ? base - p : p;
}

#define MFMA16(A,B,C) __builtin_amdgcn_mfma_f32_16x16x32_bf16((A),(B),(C),0,0,0)

typedef __attribute__((address_space(1))) const unsigned int gu32;
typedef __attribute__((address_space(3))) unsigned int lu32;
__device__ __forceinline__ void gl_lds16(const unsigned short* g, char* l){
  __builtin_amdgcn_global_load_lds((gu32*)(const void*)g, (lu32*)(void*)l, 16, 0, 0);
}

// ---------------- LDS layout (bytes) — 161280 <= 160KiB, 512 thr, 1 WG/CU ----------------
#define OXFT 0          // f32 [64 dims][132] x-state transposed
#define XFT_S 132
#define OXHB 33792      // bf16 [128 batch][40] current x-half, batch-major (xk source)
#define XHB_S 40
#define OHB  44032      // bf16 [128 batch][136] hidden chunk; slots 0,1 alias (17408B each)
#define HB_S 136
#define OW1  78848      // 2 x 40960B W1 chunk double buffer, frag-linear (40 tiles x 1KB)
#define W1BUF 40960
#define OLJ  160768     // f32[128]
#define SM_SZ 161280
// reduce slots: bf16 [128][68] (17408B). Slots 0,1 alias HB; slots 2,3 alias W1 buf1.
// Liveness (r10-proven): written after chunk-3 barrier (HB + buf1 dead; next-MLP chunk0
// DMA -> buf0); consumed in coupling; buf1's next DMA (chunk1 of next MLP, issued at top
// of its chunk0) comes only after the coupling barrier.
#define SL_S 68
#define SLOT_B 17408

// ws (bf16, fragment-linear): W1 [24][4 chunks][40 tiles][512], W2 [24][4 c][4 hw][4 ot][512]
#define WF_W2 1966080
#define W_TOTAL 2752512

// -------- one-time f32 -> bf16 fragment-linear rearrangement, SOURCE-LINEAR --------
// W1: thread covers src 8 elems at (m, c*128+h, lqkk): src=(c*128+h)*160+lqkk*8 (coalesced)
// W2: thread covers src 8 elems at (m, o, chl):        src=o*512+chl*8          (coalesced)
#define NT_W1 245760   // 24*4*128*20
#define NT_W2 98304    // 24*64*64
__global__ void cvtw_lin(const float* __restrict__ s1w1, const float* __restrict__ s1w2,
                         const float* __restrict__ s2w1, const float* __restrict__ s2w2,
                         unsigned short* __restrict__ dst)
{
  int t = blockIdx.x * blockDim.x + threadIdx.x;
  if (t < NT_W1){
    int lqkk = t % 20;  int u2 = t / 20;
    int h = u2 & 127;   int mc = u2 >> 7;
    int c = mc & 3,  m = mc >> 2;
    int kk = lqkk >> 2, lq = lqkk & 3;
    int rg = h >> 4, l15 = h & 15;
    const float* src = ((m & 1) ? s1w1 : s2w1) + (size_t)(m >> 1)*81920
                       + (size_t)(c*128 + h)*160 + lqkk*8;   // FIX: + c*128 row offset
    f4v a = *(const f4v*)src;
    f4v b = *(const f4v*)(src + 4);
    u4v o = {cpk(a[0],a[1]), cpk(a[2],a[3]), cpk(b[0],b[1]), cpk(b[2],b[3])};
    *(u4v*)(dst + (size_t)m*81920 + c*20480 + (rg*5 + kk)*512 + (lq*16 + l15)*8) = o;
  } else if (t < NT_W1 + NT_W2){
    int v = t - NT_W1;
    int chl = v & 63;  int u2 = v >> 6;
    int ol = u2 & 63;  int m = u2 >> 6;
    int c = chl >> 4, hw = (chl >> 2) & 3, lq = chl & 3;
    int ot = ol >> 4, l15 = ol & 15;
    const float* src = ((m & 1) ? s1w2 : s2w2) + (size_t)(m >> 1)*32768 + (ot*16 + l15)*512 + chl*8;
    f4v a = *(const f4v*)src;
    f4v b = *(const f4v*)(src + 4);
    u4v o = {cpk(a[0],a[1]), cpk(a[2],a[3]), cpk(b[0],b[1]), cpk(b[2],b[3])};
    *(u4v*)(dst + WF_W2 + (size_t)m*32768 + ((c*4 + hw)*4 + ot)*512 + (lq*16 + l15)*8) = o;
  }
}

__global__ __launch_bounds__(512, 1) void cinn_dma(
    const float* __restrict__ q, const float* __restrict__ Hg,
    const int* __restrict__ perms,
    const float* __restrict__ ls_g, const float* __restrict__ bi_g,
    const float* __restrict__ s1b1, const float* __restrict__ s1b2,
    const float* __restrict__ s2b1, const float* __restrict__ s2b2,
    const unsigned short* __restrict__ wbf,
    float* __restrict__ outz, float* __restrict__ outlj)
{
  __shared__ __align__(16) char sm[SM_SZ];
  const int tid = threadIdx.x;
  const int rowbase = blockIdx.x * 128;
  const int lane = tid & 63, wave = tid >> 6;
  const int hw = wave >> 1, ng = wave & 1;     // hw: k-split / hidden group; ng: batch half
  const int l15 = lane & 15, lq = lane >> 4;

  float* XFT = (float*)(sm + OXFT);
  short* XHB = (short*)(sm + OXHB);
  short* HB  = (short*)(sm + OHB);
  float* LOGJ= (float*)(sm + OLJ);

  // init XFT from q (coalesced read, strided LDS write, once)
  {
    int b = tid >> 2, j = tid & 3;
    const float* src = q + (size_t)(rowbase + b)*64 + j*16;
    #pragma unroll
    for (int i = 0; i < 4; ++i){
      f4v v = *(const f4v*)(src + 4*i);
      #pragma unroll
      for (int jj = 0; jj < 4; ++jj)
        XFT[(j*16 + 4*i + jj)*XFT_S + b] = v[jj];
    }
  }
  if (tid < 128) LOGJ[tid] = 0.f;
  __syncthreads();

  // H-part B-fragments: loaded ONCE, register-resident (4 nt x 4 kk)
  s8v hfr[4][4];
  #pragma unroll
  for (int nt = 0; nt < 4; ++nt){
    int b = rowbase + ng*64 + nt*16 + l15;
    #pragma unroll
    for (int kkh = 0; kkh < 4; ++kkh){
      const float* hp = Hg + (size_t)b*128 + kkh*32 + lq*8;
      f4v a = *(const f4v*)hp;
      f4v c = *(const f4v*)(hp + 4);
      u4v u = {cpk(a[0],a[1]), cpk(a[2],a[3]), cpk(c[0],c[1]), cpk(c[2],c[3])};
      hfr[nt][kkh] = __builtin_bit_cast(s8v, u);
    }
  }

  // prologue: DMA MLP0 chunk0 -> buf0 (drained by the m=0 permute barriers)
  {
    const unsigned short* g = wbf + wave*2560 + lane*8;
    char* lb = sm + OW1 + wave*5120;
    #pragma unroll
    for (int k = 0; k < 5; ++k) gl_lds16(g + k*512, lb + k*1024);
  }

  for (int m = 0; m < 24; ++m){
    const int bp = m & 1;
    const unsigned short* w1sec = wbf + (size_t)m*81920;
    const unsigned short* w2sec = wbf + WF_W2 + (size_t)m*32768;
    const float* b1p = (bp ? s1b1 : s2b1) + (m >> 1)*512;
    const float* b2p = (bp ? s1b2 : s2b2) + (m >> 1)*64;

    if (!bp){
      int blk = m >> 1;
      // per-thread table reads (L2-hot, wave-redundant)
      int   pd = perms[blk*64 + lane];
      float e  = __expf(ls_g[blk*64 + lane]);
      float bi = bi_g[blk*64 + lane];
      int bg = wave;                        // 8 groups x 16 batch
      f4v v[4];
      #pragma unroll
      for (int i = 0; i < 4; ++i)
        v[i] = *(const f4v*)(XFT + pd*XFT_S + bg*16 + 4*i);
      __syncthreads();
      #pragma unroll
      for (int i = 0; i < 4; ++i){
        #pragma unroll
        for (int jj = 0; jj < 4; ++jj) v[i][jj] = fmaf(v[i][jj], e, bi);
        *(f4v*)(XFT + lane*XFT_S + bg*16 + 4*i) = v[i];
      }
      if (lane >= 32){    // x2 -> XHB (even MLP's x-input)
        #pragma unroll
        for (int i = 0; i < 4; ++i)
          #pragma unroll
          for (int jj = 0; jj < 4; ++jj)
            XHB[(bg*16 + 4*i + jj)*XHB_S + (lane - 32)] = f2bf(v[i][jj]);
      }
      __syncthreads();
    }

    // xk: one b128 per nt from XHB (batch-major bf16)
    s8v xk[4];
    #pragma unroll
    for (int nt = 0; nt < 4; ++nt)
      xk[nt] = *(const s8v*)(XHB + (ng*64 + nt*16 + l15)*XHB_S + lq*8);

    // GEMM2 accumulators: bias-init on hw==0, zero otherwise
    f4v racc[4][4];
    #pragma unroll
    for (int ot = 0; ot < 4; ++ot){
      f4v bv = (f4v){0.f,0.f,0.f,0.f};
      if (hw == 0) bv = *(const f4v*)(b2p + ot*16 + lq*4);
      #pragma unroll
      for (int nt = 0; nt < 4; ++nt) racc[ot][nt] = bv;
    }

    #pragma unroll
    for (int c = 0; c < 4; ++c){
      // DMA next chunk into the other buffer (full chunk of compute covers it)
      if (!(m == 23 && c == 3)){
        const unsigned short* gsec = (c < 3) ? (w1sec + (c+1)*20480) : (w1sec + 81920);
        const unsigned short* g = gsec + wave*2560 + lane*8;
        char* lb = sm + OW1 + ((c+1)&1)*W1BUF + wave*5120;
        #pragma unroll
        for (int k = 0; k < 5; ++k) gl_lds16(g + k*512, lb + k*1024);
      }
      // W2 A-frags (frag-linear, coalesced 1KB/wave)
      s8v w2c[4];
      #pragma unroll
      for (int ot = 0; ot < 4; ++ot)
        w2c[ot] = *(const s8v*)(w2sec + (size_t)((c*4 + hw)*4 + ot)*512 + lane*8);

      // ---- GEMM1 chunk c: hidden rows hw*32 + {0,16}, bias-init accumulators
      const short* W1c = (const short*)(sm + OW1 + (c&1)*W1BUF);
      f4v acc[2][4];
      {
        f4v b1v0 = *(const f4v*)(b1p + c*128 + hw*32 + lq*4);
        f4v b1v1 = *(const f4v*)(b1p + c*128 + hw*32 + 16 + lq*4);
        #pragma unroll
        for (int nt = 0; nt < 4; ++nt){ acc[0][nt] = b1v0; acc[1][nt] = b1v1; }
      }
      #pragma unroll
      for (int kk = 0; kk < 5; ++kk){
        s8v a0 = *(const s8v*)(W1c + ((hw*2 + 0)*5 + kk)*512 + lane*8);
        s8v a1 = *(const s8v*)(W1c + ((hw*2 + 1)*5 + kk)*512 + lane*8);
        #pragma unroll
        for (int nt = 0; nt < 4; ++nt){
          s8v bb = (kk == 0) ? xk[nt] : hfr[nt][kk-1];
          acc[0][nt] = MFMA16(a0, bb, acc[0][nt]);
          acc[1][nt] = MFMA16(a1, bb, acc[1][nt]);
        }
      }
      // relu + pack -> own HB region (in-wave)
      #pragma unroll
      for (int mt = 0; mt < 2; ++mt)
        #pragma unroll
        for (int nt = 0; nt < 4; ++nt){
          float h0 = fmaxf(acc[mt][nt][0], 0.f);
          float h1 = fmaxf(acc[mt][nt][1], 0.f);
          float h2 = fmaxf(acc[mt][nt][2], 0.f);
          float h3 = fmaxf(acc[mt][nt][3], 0.f);
          *(u2v*)(HB + (ng*64 + nt*16 + l15)*HB_S + hw*32 + mt*16 + lq*4) = (u2v){cpk(h0,h1), cpk(h2,h3)};
        }
      // ---- GEMM2 k-slice: read back OWN 32 rows (in-wave, no barrier)
      #pragma unroll
      for (int nt = 0; nt < 4; ++nt){
        s8v bb = *(const s8v*)(HB + (ng*64 + nt*16 + l15)*HB_S + hw*32 + lq*8);
        #pragma unroll
        for (int ot = 0; ot < 4; ++ot)
          racc[ot][nt] = MFMA16(w2c[ot], bb, racc[ot][nt]);
      }
      __syncthreads();   // buf(c&1) free; buf((c+1)&1) DMA drained
    }

    // ---- 4 reduce slots (0,1 alias dead HB; 2,3 alias dead W1 buf1)
    {
      short* SL = (hw < 2) ? (short*)(sm + OHB + hw*SLOT_B)
                           : (short*)(sm + OW1 + W1BUF + (hw-2)*SLOT_B);
      #pragma unroll
      for (int ot = 0; ot < 4; ++ot)
        #pragma unroll
        for (int nt = 0; nt < 4; ++nt)
          *(u2v*)(SL + (ng*64 + nt*16 + l15)*SL_S + ot*16 + lq*4) =
            (u2v){cpk(racc[ot][nt][0], racc[ot][nt][1]), cpk(racc[ot][nt][2], racc[ot][nt][3])};
    }
    __syncthreads();

    // ---- coupling: sum 4 slots, le = 0.636*atan(rL); y = exp(le)*x_half + rR
    {
      int b = tid & 127, og = tid >> 7;            // 4 dim-groups x 8 dims
      float le[8] = {0,0,0,0,0,0,0,0}, ra[8] = {0,0,0,0,0,0,0,0};
      #pragma unroll
      for (int ms = 0; ms < 4; ++ms){
        const short* SL = (ms < 2) ? (const short*)(sm + OHB + ms*SLOT_B)
                                   : (const short*)(sm + OW1 + W1BUF + (ms-2)*SLOT_B);
        u2v L0 = *(const u2v*)(SL + b*SL_S + og*8);
        u2v L1 = *(const u2v*)(SL + b*SL_S + og*8 + 4);
        u2v R0 = *(const u2v*)(SL + b*SL_S + 32 + og*8);
        u2v R1 = *(const u2v*)(SL + b*SL_S + 32 + og*8 + 4);
        le[0]+=bf_lo(L0[0]); le[1]+=bf_hi(L0[0]); le[2]+=bf_lo(L0[1]); le[3]+=bf_hi(L0[1]);
        le[4]+=bf_lo(L1[0]); le[5]+=bf_hi(L1[0]); le[6]+=bf_lo(L1[1]); le[7]+=bf_hi(L1[1]);
        ra[0]+=bf_lo(R0[0]); ra[1]+=bf_hi(R0[0]); ra[2]+=bf_lo(R0[1]); ra[3]+=bf_hi(R0[1]);
        ra[4]+=bf_lo(R1[0]); ra[5]+=bf_hi(R1[0]); ra[6]+=bf_lo(R1[1]); ra[7]+=bf_hi(R1[1]);
      }
      float part = 0.f, y[8];
      #pragma unroll
      for (int j = 0; j < 8; ++j){
        float l = 0.636f * atan_f(le[j]);
        int d = bp*32 + og*8 + j;
        y[j] = __expf(l) * XFT[d*XFT_S + b] + ra[j];
        XFT[d*XFT_S + b] = y[j];
        part += l;
      }
      if (!bp)   // y1 feeds the odd MLP's xk
        *(u4v*)(XHB + b*XHB_S + og*8) = (u4v){cpk(y[0],y[1]), cpk(y[2],y[3]), cpk(y[4],y[5]), cpk(y[6],y[7])};
      atomicAdd(&LOGJ[b], part);
    }
    __syncthreads();   // slots consumed; next MLP c=0 may DMA into buf1
  }

  // output: transpose back, coalesced global writes
  {
    int b = tid >> 2, j = tid & 3;
    float* dst = outz + (size_t)(rowbase + b)*64 + j*16;
    #pragma unroll
    for (int i = 0; i < 4; ++i){
      f4v w;
      #pragma unroll
      for (int jj = 0; jj < 4; ++jj)
        w[jj] = XFT[(j*16 + 4*i + jj)*XFT_S + b];
      *(f4v*)(dst + 4*i) = w;
    }
  }
  if (tid < 128){
    float p = 0.f;
    #pragma unroll
    for (int k = 0; k < 12; ++k) p += ls_g[k*64 + lane];
    #pragma unroll
    for (int off = 1; off < 64; off <<= 1) p += __shfl_xor(p, off);
    outlj[rowbase + tid] = LOGJ[tid] + p;
  }
}

extern "C" void kernel_launch(void* const* d_in, const int* in_sizes, int n_in,
                              void* d_out, int out_size, void* d_ws, size_t ws_size,
                              hipStream_t stream)
{
  const float* q    = (const float*)d_in[0];
  const float* Hg   = (const float*)d_in[1];
  const int*   perms= (const int*)  d_in[2];
  const float* ls   = (const float*)d_in[3];
  const float* bi   = (const float*)d_in[4];
  const float* s1W1 = (const float*)d_in[5];
  const float* s1b1 = (const float*)d_in[6];
  const float* s1W2 = (const float*)d_in[7];
  const float* s1b2 = (const float*)d_in[8];
  const float* s2W1 = (const float*)d_in[9];
  const float* s2b1 = (const float*)d_in[10];
  const float* s2W2 = (const float*)d_in[11];
  const float* s2b2 = (const float*)d_in[12];
  float* outz  = (float*)d_out;
  float* outlj = outz + (size_t)B_ROWS * 64;

  unsigned short* wbf = (unsigned short*)d_ws;
  cvtw_lin<<<1344, 256, 0, stream>>>(s1W1, s1W2, s2W1, s2W2, wbf);
  cinn_dma<<<256, 512, 0, stream>>>(q, Hg, perms, ls, bi,
                                    s1b1, s1b2, s2b1, s2b2,
                                    wbf, outz, outlj);
}